// Round 4
// baseline (29.119 us; speedup 1.0000x reference)
//
#include <hip/hip_runtime.h>

// out[n][f] = class_bias[f][ idx[n][f] ] + global_bias[f]
// N=1048576, F=16, C=1024.
// R3: LDS-staged table = 27.7 us (from 52.9). Remaining gap vs 21.3 us BW
// floor: staging ramp + per-iteration vmcnt/lgkmcnt serialization at 2-deep.
// R4: 4-deep batching (4 independent idx loads hoisted above all gathers),
// __launch_bounds__(1024,8) pins VGPR<=64 -> 2 blocks/CU = 32 waves (100%).

constexpr int kC = 1024;
constexpr int kF = 16;
constexpr int kTab = kF * kC;          // 16384 floats = 64 KiB

typedef int   v4i __attribute__((ext_vector_type(4)));
typedef float v4f __attribute__((ext_vector_type(4)));

__global__ __launch_bounds__(1024, 8) void onehot_lds_kernel(
    const v4i* __restrict__ idx4,
    const v4f* __restrict__ cb4,       // [16][1024] f32 viewed as v4f
    const float* __restrict__ gb,      // [16]
    v4f* __restrict__ out4,
    int total4)                        // (N*F)/4
{
    __shared__ float lut[kTab];

    // Stage table with bias fused: 16384 floats / 1024 threads = 4 v4f each.
    {
        v4f* lut4 = (v4f*)lut;
        #pragma unroll
        for (int j = 0; j < 4; ++j) {
            int p = threadIdx.x + j * 1024;      // v4f slot in [0, 4096)
            v4f v = cb4[p];
            float b = gb[p >> 8];                // 256 v4f per feature row
            v.x += b; v.y += b; v.z += b; v.w += b;
            lut4[p] = v;
        }
    }
    __syncthreads();

    const int S = gridDim.x * blockDim.x;  // blockDim=1024 -> S % 4 == 0 always
    int t = blockIdx.x * blockDim.x + threadIdx.x;
    // f0 = feature group of element t*4; invariant under t += k*S since S%4==0.
    const int f0 = (t & 3) << 2;
    const float* __restrict__ base = lut + f0 * kC;

    // 4-deep batch: all 4 idx loads issued before any gather/store.
    for (; t + 3 * S < total4; t += 4 * S) {
        v4i a0 = __builtin_nontemporal_load(&idx4[t]);
        v4i a1 = __builtin_nontemporal_load(&idx4[t + S]);
        v4i a2 = __builtin_nontemporal_load(&idx4[t + 2 * S]);
        v4i a3 = __builtin_nontemporal_load(&idx4[t + 3 * S]);
        v4f o0, o1, o2, o3;
        o0.x = base[a0.x]; o0.y = base[kC + a0.y]; o0.z = base[2 * kC + a0.z]; o0.w = base[3 * kC + a0.w];
        o1.x = base[a1.x]; o1.y = base[kC + a1.y]; o1.z = base[2 * kC + a1.z]; o1.w = base[3 * kC + a1.w];
        o2.x = base[a2.x]; o2.y = base[kC + a2.y]; o2.z = base[2 * kC + a2.z]; o2.w = base[3 * kC + a2.w];
        o3.x = base[a3.x]; o3.y = base[kC + a3.y]; o3.z = base[2 * kC + a3.z]; o3.w = base[3 * kC + a3.w];
        __builtin_nontemporal_store(o0, &out4[t]);
        __builtin_nontemporal_store(o1, &out4[t + S]);
        __builtin_nontemporal_store(o2, &out4[t + 2 * S]);
        __builtin_nontemporal_store(o3, &out4[t + 3 * S]);
    }
    for (; t < total4; t += S) {
        v4i a = __builtin_nontemporal_load(&idx4[t]);
        v4f o;
        o.x = base[a.x]; o.y = base[kC + a.y]; o.z = base[2 * kC + a.z]; o.w = base[3 * kC + a.w];
        __builtin_nontemporal_store(o, &out4[t]);
    }
}

extern "C" void kernel_launch(void* const* d_in, const int* in_sizes, int n_in,
                              void* d_out, int out_size, void* d_ws, size_t ws_size,
                              hipStream_t stream) {
    const v4i* idx4 = (const v4i*)d_in[0];      // [N,F] int32 viewed as v4i
    const v4f* cb4  = (const v4f*)d_in[1];      // [F,C] f32
    const float* gb = (const float*)d_in[2];    // [F] f32
    v4f* out4 = (v4f*)d_out;

    const int total4 = out_size / 4;            // 4,194,304
    const int block  = 1024;                    // 16 waves; 64 KiB LDS -> 2 blk/CU
    const int grid   = 512;                     // 2 per CU; 8 elements/thread
    onehot_lds_kernel<<<grid, block, 0, stream>>>(idx4, cb4, gb, out4, total4);
}

// Round 5
// 27.834 us; speedup vs baseline: 1.0462x; 1.0462x over previous
//
#include <hip/hip_runtime.h>

// out[n][f] = class_bias[f][ idx[n][f] ] + global_bias[f]
// N=1048576, F=16, C=1024.
// R3 (2-deep LDS-staged): 27.7 us. R4 (4-deep): 29.1 us — regression, reverted.
// R5: R3 structure + software-pipelined idx prefetch (next pair issued before
// current pair's gathers) + prologue idx loads issued BEFORE staging loads so
// the first gather's vmcnt is satisfied when the barrier drops.
// Traffic floor: 64 MB idx read + 64 MB out write ~= 21.3 us @6.3 TB/s.

constexpr int kC = 1024;
constexpr int kF = 16;
constexpr int kTab = kF * kC;          // 16384 floats = 64 KiB

typedef int   v4i __attribute__((ext_vector_type(4)));
typedef float v4f __attribute__((ext_vector_type(4)));

__global__ __launch_bounds__(1024) void onehot_lds_kernel(
    const v4i* __restrict__ idx4,
    const v4f* __restrict__ cb4,       // [16][1024] f32 viewed as v4f
    const float* __restrict__ gb,      // [16]
    v4f* __restrict__ out4,
    int total4)                        // (N*F)/4
{
    __shared__ float lut[kTab];

    const int S = gridDim.x * blockDim.x;  // 524288; S % 4 == 0
    int t = blockIdx.x * blockDim.x + threadIdx.x;
    const int f0 = (t & 3) << 2;           // invariant under t += k*S
    const float* __restrict__ base = lut + f0 * kC;

    // Prologue: issue first idx pair BEFORE staging loads (latency hides
    // under the 64 KiB table fetch + barrier).
    v4i a0, a1;
    bool have = (t + S) < total4;
    if (have) {
        a0 = __builtin_nontemporal_load(&idx4[t]);
        a1 = __builtin_nontemporal_load(&idx4[t + S]);
    }

    // Stage table with bias fused: 16384 floats / 1024 threads = 4 v4f each.
    {
        v4f* lut4 = (v4f*)lut;
        #pragma unroll
        for (int j = 0; j < 4; ++j) {
            int p = threadIdx.x + j * 1024;      // v4f slot in [0, 4096)
            v4f v = cb4[p];
            float b = gb[p >> 8];                // 256 v4f per feature row
            v.x += b; v.y += b; v.z += b; v.w += b;
            lut4[p] = v;
        }
    }
    __syncthreads();

    // Pipelined 2-deep loop: prefetch pair k+1, then gather/store pair k.
    while (have) {
        const int tn = t + 2 * S;
        const bool haven = (tn + S) < total4;
        v4i b0, b1;
        if (haven) {
            b0 = __builtin_nontemporal_load(&idx4[tn]);
            b1 = __builtin_nontemporal_load(&idx4[tn + S]);
        }
        v4f o0, o1;
        o0.x = base[a0.x]; o0.y = base[kC + a0.y];
        o0.z = base[2 * kC + a0.z]; o0.w = base[3 * kC + a0.w];
        __builtin_nontemporal_store(o0, &out4[t]);
        o1.x = base[a1.x]; o1.y = base[kC + a1.y];
        o1.z = base[2 * kC + a1.z]; o1.w = base[3 * kC + a1.w];
        __builtin_nontemporal_store(o1, &out4[t + S]);
        t = tn; a0 = b0; a1 = b1; have = haven;
    }
    // Tail (never runs at our launch: total4 / S == 8 exactly).
    for (; t < total4; t += S) {
        v4i a = __builtin_nontemporal_load(&idx4[t]);
        v4f o;
        o.x = base[a.x]; o.y = base[kC + a.y];
        o.z = base[2 * kC + a.z]; o.w = base[3 * kC + a.w];
        __builtin_nontemporal_store(o, &out4[t]);
    }
}

extern "C" void kernel_launch(void* const* d_in, const int* in_sizes, int n_in,
                              void* d_out, int out_size, void* d_ws, size_t ws_size,
                              hipStream_t stream) {
    const v4i* idx4 = (const v4i*)d_in[0];      // [N,F] int32 viewed as v4i
    const v4f* cb4  = (const v4f*)d_in[1];      // [F,C] f32
    const float* gb = (const float*)d_in[2];    // [F] f32
    v4f* out4 = (v4f*)d_out;

    const int total4 = out_size / 4;            // 4,194,304
    const int block  = 1024;                    // 16 waves; 64 KiB LDS -> 2 blk/CU
    const int grid   = 512;                     // 2 per CU; 8 int4 per thread
    onehot_lds_kernel<<<grid, block, 0, stream>>>(idx4, cb4, gb, out4, total4);
}

// Round 6
// 26.145 us; speedup vs baseline: 1.1137x; 1.0646x over previous
//
#include <hip/hip_runtime.h>

// out[n][f] = class_bias[f][ idx[n][f] ] + global_bias[f]
// N=1048576, F=16, C=1024.
// R3 (LDS-staged, nt loads/stores): 27.7 us. R4 4-deep: 29.1 (reverted).
// R5 sw-pipeline: 27.8 (neutral).
// R6 theory: idx(64MiB)+out(64MiB) = 128MiB fits the 256MiB Infinity Cache.
// Graph replays reuse the same buffers -> with CACHEABLE accesses the steady
// state runs out of L3 (R0 already showed FETCH=32MiB < 64MiB idx). The nt
// hints forced every byte to HBM. Drop them.

constexpr int kC = 1024;
constexpr int kF = 16;
constexpr int kTab = kF * kC;          // 16384 floats = 64 KiB

typedef int   v4i __attribute__((ext_vector_type(4)));
typedef float v4f __attribute__((ext_vector_type(4)));

__global__ __launch_bounds__(1024) void onehot_lds_kernel(
    const v4i* __restrict__ idx4,
    const v4f* __restrict__ cb4,       // [16][1024] f32 viewed as v4f
    const float* __restrict__ gb,      // [16]
    v4f* __restrict__ out4,
    int total4)                        // (N*F)/4
{
    __shared__ float lut[kTab];

    // Stage table with bias fused: 16384 floats / 1024 threads = 4 v4f each.
    {
        v4f* lut4 = (v4f*)lut;
        #pragma unroll
        for (int j = 0; j < 4; ++j) {
            int p = threadIdx.x + j * 1024;      // v4f slot in [0, 4096)
            v4f v = cb4[p];
            float b = gb[p >> 8];                // 256 v4f per feature row
            v.x += b; v.y += b; v.z += b; v.w += b;
            lut4[p] = v;
        }
    }
    __syncthreads();

    const int S = gridDim.x * blockDim.x;  // 524288; S % 4 == 0
    int t = blockIdx.x * blockDim.x + threadIdx.x;
    const int f0 = (t & 3) << 2;           // invariant under t += k*S
    const float* __restrict__ base = lut + f0 * kC;

    // 2-deep batched grid-stride (cacheable loads/stores — let L3 work).
    for (; t + S < total4; t += 2 * S) {
        v4i a = idx4[t];
        v4i b = idx4[t + S];
        v4f oa, ob;
        oa.x = base[a.x]; oa.y = base[kC + a.y];
        oa.z = base[2 * kC + a.z]; oa.w = base[3 * kC + a.w];
        ob.x = base[b.x]; ob.y = base[kC + b.y];
        ob.z = base[2 * kC + b.z]; ob.w = base[3 * kC + b.w];
        out4[t] = oa;
        out4[t + S] = ob;
    }
    for (; t < total4; t += S) {
        v4i a = idx4[t];
        v4f o;
        o.x = base[a.x]; o.y = base[kC + a.y];
        o.z = base[2 * kC + a.z]; o.w = base[3 * kC + a.w];
        out4[t] = o;
    }
}

extern "C" void kernel_launch(void* const* d_in, const int* in_sizes, int n_in,
                              void* d_out, int out_size, void* d_ws, size_t ws_size,
                              hipStream_t stream) {
    const v4i* idx4 = (const v4i*)d_in[0];      // [N,F] int32 viewed as v4i
    const v4f* cb4  = (const v4f*)d_in[1];      // [F,C] f32
    const float* gb = (const float*)d_in[2];    // [F] f32
    v4f* out4 = (v4f*)d_out;

    const int total4 = out_size / 4;            // 4,194,304
    const int block  = 1024;                    // 16 waves; 64 KiB LDS -> 2 blk/CU
    const int grid   = 512;                     // 2 per CU; 8 int4 per thread
    onehot_lds_kernel<<<grid, block, 0, stream>>>(idx4, cb4, gb, out4, total4);
}

// Round 7
// 26.110 us; speedup vs baseline: 1.1153x; 1.0014x over previous
//
#include <hip/hip_runtime.h>

// out[n][f] = class_bias[f][ idx[n][f] ] + global_bias[f]
// N=1048576, F=16, C=1024.
// Ladder: 52.9 (global gather) -> 27.7 (LDS-staged table, nt) -> 26.1 (all
// cacheable, R6). R4 4-deep: 29.1 (reverted); R5 sw-pipeline: 27.8 (neutral).
// R7 A/B: cacheable idx LOADS (MALL read-hits) + nt STORES (bypass L2
// write-allocate). Splits R6's win into its two halves:
//   ~25 us -> L2 write-allocate was costing; keep.
//   ~26 us -> store path irrelevant; at copy-roofline (6.3 TB/s mix).
//   ~27.5  -> MALL absorbs cacheable writes; revert.

constexpr int kC = 1024;
constexpr int kF = 16;
constexpr int kTab = kF * kC;          // 16384 floats = 64 KiB

typedef int   v4i __attribute__((ext_vector_type(4)));
typedef float v4f __attribute__((ext_vector_type(4)));

__global__ __launch_bounds__(1024) void onehot_lds_kernel(
    const v4i* __restrict__ idx4,
    const v4f* __restrict__ cb4,       // [16][1024] f32 viewed as v4f
    const float* __restrict__ gb,      // [16]
    v4f* __restrict__ out4,
    int total4)                        // (N*F)/4
{
    __shared__ float lut[kTab];

    // Stage table with bias fused: 16384 floats / 1024 threads = 4 v4f each.
    {
        v4f* lut4 = (v4f*)lut;
        #pragma unroll
        for (int j = 0; j < 4; ++j) {
            int p = threadIdx.x + j * 1024;      // v4f slot in [0, 4096)
            v4f v = cb4[p];
            float b = gb[p >> 8];                // 256 v4f per feature row
            v.x += b; v.y += b; v.z += b; v.w += b;
            lut4[p] = v;
        }
    }
    __syncthreads();

    const int S = gridDim.x * blockDim.x;  // 524288; S % 4 == 0
    int t = blockIdx.x * blockDim.x + threadIdx.x;
    const int f0 = (t & 3) << 2;           // invariant under t += k*S
    const float* __restrict__ base = lut + f0 * kC;

    // 2-deep grid-stride: cacheable loads, nontemporal stores.
    for (; t + S < total4; t += 2 * S) {
        v4i a = idx4[t];
        v4i b = idx4[t + S];
        v4f oa, ob;
        oa.x = base[a.x]; oa.y = base[kC + a.y];
        oa.z = base[2 * kC + a.z]; oa.w = base[3 * kC + a.w];
        ob.x = base[b.x]; ob.y = base[kC + b.y];
        ob.z = base[2 * kC + b.z]; ob.w = base[3 * kC + b.w];
        __builtin_nontemporal_store(oa, &out4[t]);
        __builtin_nontemporal_store(ob, &out4[t + S]);
    }
    for (; t < total4; t += S) {
        v4i a = idx4[t];
        v4f o;
        o.x = base[a.x]; o.y = base[kC + a.y];
        o.z = base[2 * kC + a.z]; o.w = base[3 * kC + a.w];
        __builtin_nontemporal_store(o, &out4[t]);
    }
}

extern "C" void kernel_launch(void* const* d_in, const int* in_sizes, int n_in,
                              void* d_out, int out_size, void* d_ws, size_t ws_size,
                              hipStream_t stream) {
    const v4i* idx4 = (const v4i*)d_in[0];      // [N,F] int32 viewed as v4i
    const v4f* cb4  = (const v4f*)d_in[1];      // [F,C] f32
    const float* gb = (const float*)d_in[2];    // [F] f32
    v4f* out4 = (v4f*)d_out;

    const int total4 = out_size / 4;            // 4,194,304
    const int block  = 1024;                    // 16 waves; 64 KiB LDS -> 2 blk/CU
    const int grid   = 512;                     // 2 per CU; 8 int4 per thread
    onehot_lds_kernel<<<grid, block, 0, stream>>>(idx4, cb4, gb, out4, total4);
}